// Round 1
// baseline (569.535 us; speedup 1.0000x reference)
//
#include <hip/hip_runtime.h>
#include <math.h>

#define H_IN 512
#define W_IN 512
#define N_ANGLES 180
#define PAD 106          // PH == PW == 106
#define P 724            // padded size

__global__ __launch_bounds__(256) void radon_kernel(
    const float* __restrict__ x,   // [512,512]
    float* __restrict__ sino,      // [180,724]
    float* __restrict__ rot)       // [180,724,724]
{
    const int block = blockIdx.x;        // 0 .. 180*724-1
    const int a = block / P;             // angle index
    const int i = block - a * P;         // output row (y)
    const int tid = threadIdx.x;

    // angle: linspace(0,180,180)[a] degrees -> radians, float32 like the ref
    const float deg = (float)a * (180.0f / 179.0f);
    const float ang = deg * (float)(M_PI / 180.0);
    float s, c;
    __sincosf(ang, &s, &c);
    // __sincosf is fast-math; use precise versions for safety:
    s = sinf(ang);
    c = cosf(ang);

    // Yn for this row (exact reference arithmetic, fp32)
    const float Yn = ((2.0f * (float)i + 1.0f) / (float)P) - 1.0f;

    float* rrow = rot + (size_t)block * P;

    float lsum = 0.0f;
    for (int j = tid; j < P; j += 256) {
        float Xn = ((2.0f * (float)j + 1.0f) / (float)P) - 1.0f;
        float xs = c * Xn - s * Yn;
        float ys = s * Xn + c * Yn;
        float ix = ((xs + 1.0f) * (float)P - 1.0f) * 0.5f;
        float iy = ((ys + 1.0f) * (float)P - 1.0f) * 0.5f;

        float x0f = floorf(ix);
        float y0f = floorf(iy);
        float wx = ix - x0f;
        float wy = iy - y0f;
        int x0 = (int)x0f;
        int y0 = (int)y0f;

        // shift into unpadded input coords; pad region of padded img is 0,
        // and out-of-[0,P) is masked to 0 by the ref -> single inner-bounds mask
        int xa = x0 - PAD, ya = y0 - PAD;
        int xb = xa + 1,   yb = ya + 1;

        float v00 = ((unsigned)xa < W_IN && (unsigned)ya < H_IN) ? x[(size_t)ya * W_IN + xa] : 0.0f;
        float v01 = ((unsigned)xb < W_IN && (unsigned)ya < H_IN) ? x[(size_t)ya * W_IN + xb] : 0.0f;
        float v10 = ((unsigned)xa < W_IN && (unsigned)yb < H_IN) ? x[(size_t)yb * W_IN + xa] : 0.0f;
        float v11 = ((unsigned)xb < W_IN && (unsigned)yb < H_IN) ? x[(size_t)yb * W_IN + xb] : 0.0f;

        float val = v00 * (1.0f - wx) * (1.0f - wy)
                  + v01 * wx          * (1.0f - wy)
                  + v10 * (1.0f - wx) * wy
                  + v11 * wx          * wy;

        __builtin_nontemporal_store(val, &rrow[j]);
        lsum += val;
    }

    // block reduction: wave64 shuffle, then cross-wave via LDS
    for (int off = 32; off > 0; off >>= 1)
        lsum += __shfl_down(lsum, off, 64);

    __shared__ float ws_red[4];
    int lane = tid & 63;
    int wid  = tid >> 6;
    if (lane == 0) ws_red[wid] = lsum;
    __syncthreads();
    if (tid == 0)
        sino[block] = ws_red[0] + ws_red[1] + ws_red[2] + ws_red[3];
}

extern "C" void kernel_launch(void* const* d_in, const int* in_sizes, int n_in,
                              void* d_out, int out_size, void* d_ws, size_t ws_size,
                              hipStream_t stream) {
    const float* x = (const float*)d_in[0];
    float* sino = (float*)d_out;                       // [180*724]
    float* rot  = sino + (size_t)N_ANGLES * P;         // [180*724*724]

    radon_kernel<<<dim3(N_ANGLES * P), dim3(256), 0, stream>>>(x, sino, rot);
}